// Round 18
// baseline (285.047 us; speedup 1.0000x reference)
//
#include <hip/hip_runtime.h>
#include <hip/hip_fp16.h>

#define NUM_GRAPHS 8192
#define BSHIFT 12
#define BSIZE 4096     // nodes per bucket
#define CHUNK 4096     // edges per chunk
#define NGRP 32        // cursor/slab groups
#define REPL 8         // aggregate window replicas
#define WINDOW 256     // max graphs spanned per bucket
#define WPAD 257       // padded replica stride
#define FNT 512        // hist_h block size
#define SGRID 2048     // scatter-role blocks in dispatch 1
#define HGRID1 2048    // h-role blocks in dispatch 1

// ===== K1 (fused): scatter into sub-slabs ∥ h = x@W over [0, Nh) ===========
__global__ void __launch_bounds__(256)
scatter_h_kernel(const int* __restrict__ src, const int* __restrict__ dst,
                 int E, int nchunks, int NBUK, int capG,
                 unsigned* __restrict__ cursor, unsigned* __restrict__ slab,
                 const float* __restrict__ x, const float* __restrict__ W,
                 float* __restrict__ h, int Nh) {
    __shared__ unsigned cnt[256];
    __shared__ unsigned lbase[256];
    __shared__ unsigned sbase[256];
    __shared__ unsigned staged[CHUNK];
    __shared__ unsigned char sbuck[CHUNK];
    __shared__ unsigned s_tot;

    int bid = blockIdx.x;
    int tid = threadIdx.x;

    if ((bid & 1) == 0) {
        // ---------------- scatter role ----------------
        int sid = bid >> 1;
        const int4* s4 = (const int4*)src;
        const int4* d4 = (const int4*)dst;
        int E4 = E >> 2;
        int g = sid & (NGRP - 1);

        for (int chunk = sid; chunk < nchunks; chunk += SGRID) {
            cnt[tid] = 0; __syncthreads();
            int b4 = chunk * (CHUNK / 4);
            int4 vd[4], vs[4];
            unsigned short r[16];
            #pragma unroll
            for (int k = 0; k < 4; ++k) {
                int idx = b4 + k * 256 + tid;
                if (idx < E4) { vd[k] = d4[idx]; vs[k] = s4[idx]; }
                else          { vd[k] = make_int4(-1, -1, -1, -1); }
            }
            #pragma unroll
            for (int k = 0; k < 4; ++k) {
                if (vd[k].x >= 0) {
                    r[4*k+0] = (unsigned short)atomicAdd(&cnt[vd[k].x >> BSHIFT], 1u);
                    r[4*k+1] = (unsigned short)atomicAdd(&cnt[vd[k].y >> BSHIFT], 1u);
                    r[4*k+2] = (unsigned short)atomicAdd(&cnt[vd[k].z >> BSHIFT], 1u);
                    r[4*k+3] = (unsigned short)atomicAdd(&cnt[vd[k].w >> BSHIFT], 1u);
                }
            }
            __syncthreads();
            if (tid < 64) {
                unsigned run = 0;
                for (int c0 = 0; c0 < 256; c0 += 64) {
                    unsigned v = cnt[c0 + tid];
                    unsigned s = v;
                    #pragma unroll
                    for (int off = 1; off < 64; off <<= 1) {
                        unsigned o = __shfl_up(s, off);
                        if (tid >= off) s += o;
                    }
                    lbase[c0 + tid] = run + s - v;
                    run += __shfl(s, 63);
                }
                if (tid == 0) s_tot = run;
            }
            if (tid < NBUK && cnt[tid])
                sbase[tid] = atomicAdd(&cursor[g * 256 + tid], cnt[tid]);
            __syncthreads();

            #pragma unroll
            for (int k = 0; k < 4; ++k) {
                if (vd[k].x >= 0) {
                    int d0 = vd[k].x, d1 = vd[k].y, d2 = vd[k].z, d3 = vd[k].w;
                    unsigned b0 = (unsigned)d0 >> BSHIFT, b1 = (unsigned)d1 >> BSHIFT;
                    unsigned b2 = (unsigned)d2 >> BSHIFT, b3 = (unsigned)d3 >> BSHIFT;
                    unsigned p0 = lbase[b0] + r[4*k+0];
                    unsigned p1 = lbase[b1] + r[4*k+1];
                    unsigned p2 = lbase[b2] + r[4*k+2];
                    unsigned p3 = lbase[b3] + r[4*k+3];
                    staged[p0] = ((unsigned)(d0 & (BSIZE-1)) << 20) | (unsigned)vs[k].x;
                    staged[p1] = ((unsigned)(d1 & (BSIZE-1)) << 20) | (unsigned)vs[k].y;
                    staged[p2] = ((unsigned)(d2 & (BSIZE-1)) << 20) | (unsigned)vs[k].z;
                    staged[p3] = ((unsigned)(d3 & (BSIZE-1)) << 20) | (unsigned)vs[k].w;
                    sbuck[p0] = (unsigned char)b0;
                    sbuck[p1] = (unsigned char)b1;
                    sbuck[p2] = (unsigned char)b2;
                    sbuck[p3] = (unsigned char)b3;
                }
            }
            __syncthreads();
            unsigned tot = s_tot;
            for (unsigned pos = tid; pos < tot; pos += 256) {
                unsigned b = sbuck[pos];
                unsigned gp = sbase[b] + (pos - lbase[b]);
                if (gp < (unsigned)capG)
                    slab[((size_t)g * NBUK + b) * capG + gp] = staged[pos];
            }
            __syncthreads();
        }
        if (sid == 0 && tid < (E & 3)) {
            int i = (E & ~3) + tid;
            int d = dst[i];
            unsigned b = (unsigned)d >> BSHIFT;
            unsigned p = atomicAdd(&cursor[b], 1u);
            if (p < (unsigned)capG)
                slab[(size_t)b * capG + p] =
                    ((unsigned)(d & (BSIZE-1)) << 20) | (unsigned)src[i];
        }
    } else {
        // ---------------- h role: nodes [0, Nh) ----------------
        int hid = bid >> 1;
        int gwave = (hid * 256 + tid) >> 6;
        int lane = tid & 63;
        int half = lane >> 5;
        int l32  = lane & 31;
        int total_waves = (HGRID1 * 256) >> 6;
        float4 wv = ((const float4*)W)[l32];
        for (int node = gwave * 2 + half; node < Nh; node += total_waves * 2) {
            float4 xv = ((const float4*)(x + (size_t)node * 128))[l32];
            float v = xv.x * wv.x + xv.y * wv.y + xv.z * wv.z + xv.w * wv.w;
            #pragma unroll
            for (int d = 16; d >= 1; d >>= 1) v += __shfl_xor(v, d);
            if (l32 == 0) h[node] = v;
        }
    }
}

// ===== K2 (fused): hist role (blocks < 2*NBUK) ∥ h over [Nh, N) =============
__global__ void __launch_bounds__(FNT)
hist_h_kernel(const unsigned* __restrict__ slab, int capG,
              const unsigned* __restrict__ cursor,
              unsigned* __restrict__ deg0, unsigned* __restrict__ deg1,
              const float* __restrict__ x, const float* __restrict__ W,
              float* __restrict__ h, int Nh, int N, int NBUK, int nhblocks) {
    __shared__ unsigned hist[BSIZE];   // 16 KB
    int bp = blockIdx.x, tid = threadIdx.x;

    if (bp < 2 * NBUK) {
        int b = bp >> 1, half = bp & 1;
        for (int t = tid; t < BSIZE; t += FNT) hist[t] = 0;
        __syncthreads();
        int g0 = half * 16;
        for (int gg = g0; gg < g0 + 16; gg += 8) {
            unsigned n[8], maxn = 0;
            const unsigned* sp[8];
            #pragma unroll
            for (int k = 0; k < 8; ++k) {
                unsigned nn = cursor[(gg + k) * 256 + b];
                if (nn > (unsigned)capG) nn = capG;
                n[k] = nn; if (nn > maxn) maxn = nn;
                sp[k] = slab + ((size_t)(gg + k) * NBUK + b) * capG;
            }
            for (unsigned i = tid; i < maxn; i += FNT) {
                unsigned e[8];
                #pragma unroll
                for (int k = 0; k < 8; ++k) e[k] = (i < n[k]) ? sp[k][i] : 0xFFFFFFFFu;
                #pragma unroll
                for (int k = 0; k < 8; ++k)
                    if (e[k] != 0xFFFFFFFFu) atomicAdd(&hist[e[k] >> 20], 1u);
            }
        }
        __syncthreads();
        int base = b << BSHIFT;
        int lim = N - base; if (lim > BSIZE) lim = BSIZE;
        unsigned* degP = half ? deg1 : deg0;
        for (int t = tid; t < lim; t += FNT) degP[base + t] = hist[t];
    } else {
        int hb = bp - 2 * NBUK;
        int gwave = (hb * FNT + tid) >> 6;
        int lane = tid & 63;
        int half = lane >> 5;
        int l32  = lane & 31;
        int total_waves = (nhblocks * FNT) >> 6;
        float4 wv = ((const float4*)W)[l32];
        for (int node = Nh + gwave * 2 + half; node < N; node += total_waves * 2) {
            float4 xv = ((const float4*)(x + (size_t)node * 128))[l32];
            float v = xv.x * wv.x + xv.y * wv.y + xv.z * wv.z + xv.w * wv.w;
            #pragma unroll
            for (int d = 16; d >= 1; d >>= 1) v += __shfl_xor(v, d);
            if (l32 == 0) h[node] = v;
        }
    }
}

// ===== K3: finalize: dinv -> hsh, pkw =======================================
__global__ void finalize_kernel(const float* __restrict__ h,
                                const unsigned* __restrict__ deg0,
                                const unsigned* __restrict__ deg1,
                                const int* __restrict__ batch,
                                unsigned short* __restrict__ hsh,
                                unsigned* __restrict__ pkw, int N) {
    int i = blockIdx.x * blockDim.x + threadIdx.x;
    int stride = gridDim.x * blockDim.x;
    for (; i < N; i += stride) {
        float di = rsqrtf((float)(deg0[i] + deg1[i] + 1u));
        hsh[i] = __half_as_ushort(__float2half(di * h[i]));
        pkw[i] = ((unsigned)batch[i] << 16) | __half_as_ushort(__float2half(di));
    }
}

// ===== K4: aggregate — quarter-blocks, 8-segment x uint2 MLP (16 in flight) =
__global__ void __launch_bounds__(512)
aggregate_kernel(const unsigned* __restrict__ slab, int capG,
                 const unsigned* __restrict__ cursor,
                 const unsigned* __restrict__ pkw,
                 const unsigned short* __restrict__ hsh,
                 float* __restrict__ pooled, int N, int NBUK) {
    __shared__ unsigned pkw_s[BSIZE];        // 16 KB
    __shared__ float win[REPL * WPAD];       // 8.2 KB
    int bp = blockIdx.x, tid = threadIdx.x;
    int b = bp >> 2, q = bp & 3;
    int base = b << BSHIFT;
    int lim = N - base; if (lim > BSIZE) lim = BSIZE;

    for (int t = tid; t < BSIZE; t += 512) pkw_s[t] = (t < lim) ? pkw[base + t] : 0u;
    for (int t = tid; t < REPL * WPAD; t += 512) win[t] = 0.0f;
    __syncthreads();
    int g_lo = (int)(pkw_s[0] >> 16);
    int g_hi = (lim > 0) ? (int)(pkw_s[lim - 1] >> 16) : g_lo;
    int width = g_hi - g_lo + 1;
    bool windowed = (width <= WINDOW);
    int r = tid & (REPL - 1);

    int n0 = q * (BSIZE / 4);
    int n1 = (q + 1) * (BSIZE / 4); if (n1 > lim) n1 = lim;
    for (int t = n0 + tid; t < n1; t += 512) {
        unsigned w = pkw_s[t];
        float di = __half2float(__ushort_as_half((unsigned short)(w & 0xFFFFu)));
        float c = di * __half2float(__ushort_as_half(hsh[base + t]));
        if (windowed) atomicAdd(&win[r * WPAD + ((w >> 16) - g_lo)], c);
        else          atomicAdd(&pooled[w >> 16], c);
    }

    // edge terms: 8 segments x uint2 loads -> 16 entries in flight per iter
    int g0 = q * 8;
    unsigned n[8], maxn = 0;
    const unsigned* sp[8];
    #pragma unroll
    for (int k = 0; k < 8; ++k) {
        unsigned nn = cursor[(g0 + k) * 256 + b];
        if (nn > (unsigned)capG) nn = capG;
        n[k] = nn; if (nn > maxn) maxn = nn;
        sp[k] = slab + ((size_t)(g0 + k) * NBUK + b) * capG;
    }
    unsigned m2 = (maxn + 1) >> 1;
    for (unsigned i2 = tid; i2 < m2; i2 += 512) {
        unsigned i0 = i2 * 2;
        uint2 ee[8];
        bool v0[8], v1[8];
        #pragma unroll
        for (int k = 0; k < 8; ++k) {
            v0[k] = (i0 < n[k]);
            v1[k] = (i0 + 1 < n[k]);
            // capG is a multiple of 4 -> uint2 load within segment bounds
            uint2 t2 = v0[k] ? ((const uint2*)sp[k])[i2] : make_uint2(0u, 0u);
            ee[k].x = v0[k] ? t2.x : 0u;
            ee[k].y = v1[k] ? t2.y : 0u;
        }
        unsigned w0[8], w1[8];
        #pragma unroll
        for (int k = 0; k < 8; ++k) {
            w0[k] = pkw_s[ee[k].x >> 20];
            w1[k] = pkw_s[ee[k].y >> 20];
        }
        unsigned short h0[8], h1[8];
        #pragma unroll
        for (int k = 0; k < 8; ++k) {
            h0[k] = hsh[ee[k].x & 0xFFFFFu];
            h1[k] = hsh[ee[k].y & 0xFFFFFu];
        }
        #pragma unroll
        for (int k = 0; k < 8; ++k) {
            float c0 = v0[k] ? __half2float(__ushort_as_half(h0[k])) *
                               __half2float(__ushort_as_half((unsigned short)(w0[k] & 0xFFFFu))) : 0.0f;
            float c1 = v1[k] ? __half2float(__ushort_as_half(h1[k])) *
                               __half2float(__ushort_as_half((unsigned short)(w1[k] & 0xFFFFu))) : 0.0f;
            if (windowed) {
                atomicAdd(&win[r * WPAD + ((w0[k] >> 16) - g_lo)], c0);
                atomicAdd(&win[r * WPAD + ((w1[k] >> 16) - g_lo)], c1);
            } else {
                if (v0[k]) atomicAdd(&pooled[w0[k] >> 16], c0);
                if (v1[k]) atomicAdd(&pooled[w1[k] >> 16], c1);
            }
        }
    }
    __syncthreads();
    if (windowed) {
        for (int g = tid; g < width; g += 512) {
            float s = 0.0f;
            #pragma unroll
            for (int rr = 0; rr < REPL; ++rr) s += win[rr * WPAD + g];
            atomicAdd(&pooled[g_lo + g], s);
        }
    }
}

// ===== K5: affine ==========================================================
__global__ void out_kernel(const float* __restrict__ pooled,
                           const float* __restrict__ pp_w,
                           const float* __restrict__ pp_b,
                           float* __restrict__ out) {
    int g = blockIdx.x * blockDim.x + threadIdx.x;
    if (g < NUM_GRAPHS) out[g] = pooled[g] * pp_w[0] + pp_b[0];
}

// ===== Fallback path (tiny ws / oversized N): correctness only =============
__global__ void deg_atomic_kernel(const int* __restrict__ dst, int E,
                                  unsigned* __restrict__ deg) {
    int tid = blockIdx.x * blockDim.x + threadIdx.x;
    int stride = gridDim.x * blockDim.x;
    for (int i = tid; i < E; i += stride) atomicAdd(&deg[dst[i]], 1u);
}

__global__ void node_fb_kernel(const float* __restrict__ x,
                               const float* __restrict__ W,
                               const unsigned* __restrict__ deg,
                               const int* __restrict__ batch,
                               unsigned short* __restrict__ hsh,
                               unsigned* __restrict__ pkw, int N) {
    int gtid = blockIdx.x * blockDim.x + threadIdx.x;
    int wave = gtid >> 6;
    int lane = threadIdx.x & 63;
    int half = lane >> 5;
    int l32  = lane & 31;
    int node = wave * 2 + half;
    if (node >= N) return;
    float4 xv = ((const float4*)(x + (size_t)node * 128))[l32];
    float4 wv = ((const float4*)W)[l32];
    float v = xv.x * wv.x + xv.y * wv.y + xv.z * wv.z + xv.w * wv.w;
    #pragma unroll
    for (int d = 16; d >= 1; d >>= 1) v += __shfl_xor(v, d);
    if (l32 == 0) {
        float di = rsqrtf((float)(deg[node] + 1u));
        hsh[node] = __half_as_ushort(__float2half(di * v));
        pkw[node] = ((unsigned)batch[node] << 16) | __half_as_ushort(__float2half(di));
    }
}

__global__ void pool_self_fb_kernel(const unsigned short* __restrict__ hsh,
                                    const unsigned* __restrict__ pkw,
                                    float* __restrict__ pooled, int N) {
    int i = blockIdx.x * blockDim.x + threadIdx.x;
    if (i >= N) return;
    unsigned w = pkw[i];
    float di = __half2float(__ushort_as_half((unsigned short)(w & 0xFFFFu)));
    atomicAdd(&pooled[w >> 16], di * __half2float(__ushort_as_half(hsh[i])));
}

__global__ void __launch_bounds__(512)
edge_direct_kernel(const int* __restrict__ src, const int* __restrict__ dst, int E,
                   const unsigned short* __restrict__ hsh,
                   const unsigned* __restrict__ pkw,
                   float* __restrict__ pooled) {
    __shared__ float pool[NUM_GRAPHS];
    for (int g = threadIdx.x; g < NUM_GRAPHS; g += 512) pool[g] = 0.0f;
    __syncthreads();
    int tid = blockIdx.x * 512 + threadIdx.x;
    int stride = gridDim.x * 512;
    for (int i = tid; i < E; i += stride) {
        unsigned w = pkw[dst[i]];
        float c = __half2float(__ushort_as_half(hsh[src[i]])) *
                  __half2float(__ushort_as_half((unsigned short)(w & 0xFFFFu)));
        atomicAdd(&pool[w >> 16], c);
    }
    __syncthreads();
    for (int g = threadIdx.x; g < NUM_GRAPHS; g += 512)
        if (pool[g] != 0.0f) atomicAdd(&pooled[g], pool[g]);
}

extern "C" void kernel_launch(void* const* d_in, const int* in_sizes, int n_in,
                              void* d_out, int out_size, void* d_ws, size_t ws_size,
                              hipStream_t stream) {
    const float* x    = (const float*)d_in[0];
    const float* W    = (const float*)d_in[1];
    const float* pp_w = (const float*)d_in[2];
    const float* pp_b = (const float*)d_in[3];
    const int*   ei   = (const int*)d_in[4];
    const int*   batch= (const int*)d_in[5];
    float* out = (float*)d_out;

    const int E = in_sizes[4] / 2;
    const int N = in_sizes[5];
    const int* src = ei;
    const int* dst = ei + E;
    int NBUK = (N + BSIZE - 1) >> BSHIFT;
    int nchunks = (E + CHUNK - 1) / CHUNK;

    char* ws = (char*)d_ws;
    size_t off = 0;
    auto alloc = [&](size_t bytes) {
        size_t o = off; off = (off + bytes + 255) & ~(size_t)255; return o;
    };
    size_t zero_bytes = (size_t)NUM_GRAPHS * 4 + (size_t)NGRP * 256 * 4;
    size_t zero_off   = alloc(zero_bytes);
    float*    pooled = (float*)(ws + zero_off);
    unsigned* cursor = (unsigned*)(ws + zero_off + (size_t)NUM_GRAPHS * 4);

    size_t h_off    = alloc((size_t)N * 4);
    size_t deg0_off = alloc((size_t)N * 4);      // also fallback deg
    size_t deg1_off = alloc((size_t)N * 4);
    size_t hsh_off  = alloc((size_t)N * 2);
    size_t pkw_off  = alloc((size_t)N * 4);

    int meanG = E / (NBUK * NGRP) + 1;
    int capG = (meanG + meanG / 8 + 512 + 3) & ~3;   // ~17 sigma, 16B-aligned
    size_t slab_off = alloc((size_t)NGRP * NBUK * (size_t)capG * 4);

    bool fast_ok = (NBUK <= 256) && (N <= (1 << 20)) && (off <= ws_size);

    float*          h    = (float*)(ws + h_off);
    unsigned*       deg0 = (unsigned*)(ws + deg0_off);
    unsigned*       deg1 = (unsigned*)(ws + deg1_off);
    unsigned short* hsh  = (unsigned short*)(ws + hsh_off);
    unsigned*       pkw  = (unsigned*)(ws + pkw_off);
    unsigned*       slab = (unsigned*)(ws + slab_off);

    hipMemsetAsync(ws + zero_off, 0, zero_bytes, stream);

    if (fast_ok) {
        // rebalanced: dispatch1 h covers 60% of nodes (t1 ~= scatter time),
        // dispatch2 h covers 40% (still >= hist time)
        int Nh = (int)(((long long)N * 3) / 5);
        scatter_h_kernel<<<SGRID + HGRID1, 256, 0, stream>>>(
            src, dst, E, nchunks, NBUK, capG, cursor, slab, x, W, h, Nh);
        int nhblocks = 2048;
        hist_h_kernel<<<2 * NBUK + nhblocks, FNT, 0, stream>>>(
            slab, capG, cursor, deg0, deg1, x, W, h, Nh, N, NBUK, nhblocks);
        finalize_kernel<<<1024, 256, 0, stream>>>(h, deg0, deg1, batch, hsh, pkw, N);
        aggregate_kernel<<<4 * NBUK, 512, 0, stream>>>(slab, capG, cursor, pkw,
                                                       hsh, pooled, N, NBUK);
    } else {
        hipMemsetAsync(deg0, 0, (size_t)N * 4, stream);
        deg_atomic_kernel<<<2048, 256, 0, stream>>>(dst, E, deg0);
        int node_blocks = (N + 7) / 8;
        node_fb_kernel<<<node_blocks, 256, 0, stream>>>(x, W, deg0, batch, hsh, pkw, N);
        pool_self_fb_kernel<<<(N + 255) / 256, 256, 0, stream>>>(hsh, pkw, pooled, N);
        edge_direct_kernel<<<512, 512, 0, stream>>>(src, dst, E, hsh, pkw, pooled);
    }

    out_kernel<<<(NUM_GRAPHS + 255) / 256, 256, 0, stream>>>(pooled, pp_w, pp_b, out);
}

// Round 19
// 270.420 us; speedup vs baseline: 1.0541x; 1.0541x over previous
//
#include <hip/hip_runtime.h>
#include <hip/hip_fp16.h>

#define NUM_GRAPHS 8192
#define BSHIFT 12
#define BSIZE 4096     // nodes per bucket
#define CHUNK 4096     // edges per chunk
#define NGRP 32        // cursor/slab groups
#define REPL 8         // aggregate window replicas
#define WINDOW 256     // max graphs spanned per bucket
#define WPAD 257       // padded replica stride
#define FNT 512        // hist_h block size
#define SGRID 2048     // scatter-role blocks in dispatch 1
#define HGRID1 2048    // h-role blocks in dispatch 1

// ===== K1 (fused): scatter into sub-slabs ∥ h = x@W over [0, Nh) ===========
// Roles interleaved by bid&1; scatter LDS 21.2KB -> ~7 blocks/CU mixed.
__global__ void __launch_bounds__(256)
scatter_h_kernel(const int* __restrict__ src, const int* __restrict__ dst,
                 int E, int nchunks, int NBUK, int capG,
                 unsigned* __restrict__ cursor, unsigned* __restrict__ slab,
                 const float* __restrict__ x, const float* __restrict__ W,
                 float* __restrict__ h, int Nh) {
    __shared__ unsigned cnt[256];
    __shared__ unsigned lbase[256];
    __shared__ unsigned sbase[256];
    __shared__ unsigned staged[CHUNK];
    __shared__ unsigned char sbuck[CHUNK];
    __shared__ unsigned s_tot;

    int bid = blockIdx.x;
    int tid = threadIdx.x;

    if ((bid & 1) == 0) {
        // ---------------- scatter role: sid in [0, SGRID) -------------------
        int sid = bid >> 1;
        const int4* s4 = (const int4*)src;
        const int4* d4 = (const int4*)dst;
        int E4 = E >> 2;
        int g = sid & (NGRP - 1);

        for (int chunk = sid; chunk < nchunks; chunk += SGRID) {
            cnt[tid] = 0; __syncthreads();
            int b4 = chunk * (CHUNK / 4);
            int4 vd[4], vs[4];
            unsigned short r[16];
            #pragma unroll
            for (int k = 0; k < 4; ++k) {
                int idx = b4 + k * 256 + tid;
                if (idx < E4) { vd[k] = d4[idx]; vs[k] = s4[idx]; }
                else          { vd[k] = make_int4(-1, -1, -1, -1); }
            }
            #pragma unroll
            for (int k = 0; k < 4; ++k) {
                if (vd[k].x >= 0) {
                    r[4*k+0] = (unsigned short)atomicAdd(&cnt[vd[k].x >> BSHIFT], 1u);
                    r[4*k+1] = (unsigned short)atomicAdd(&cnt[vd[k].y >> BSHIFT], 1u);
                    r[4*k+2] = (unsigned short)atomicAdd(&cnt[vd[k].z >> BSHIFT], 1u);
                    r[4*k+3] = (unsigned short)atomicAdd(&cnt[vd[k].w >> BSHIFT], 1u);
                }
            }
            __syncthreads();
            // wave0: exclusive scan of cnt -> lbase
            if (tid < 64) {
                unsigned run = 0;
                for (int c0 = 0; c0 < 256; c0 += 64) {
                    unsigned v = cnt[c0 + tid];
                    unsigned s = v;
                    #pragma unroll
                    for (int off = 1; off < 64; off <<= 1) {
                        unsigned o = __shfl_up(s, off);
                        if (tid >= off) s += o;
                    }
                    lbase[c0 + tid] = run + s - v;
                    run += __shfl(s, 63);
                }
                if (tid == 0) s_tot = run;
            }
            if (tid < NBUK && cnt[tid])
                sbase[tid] = atomicAdd(&cursor[g * 256 + tid], cnt[tid]);
            __syncthreads();

            #pragma unroll
            for (int k = 0; k < 4; ++k) {
                if (vd[k].x >= 0) {
                    int d0 = vd[k].x, d1 = vd[k].y, d2 = vd[k].z, d3 = vd[k].w;
                    unsigned b0 = (unsigned)d0 >> BSHIFT, b1 = (unsigned)d1 >> BSHIFT;
                    unsigned b2 = (unsigned)d2 >> BSHIFT, b3 = (unsigned)d3 >> BSHIFT;
                    unsigned p0 = lbase[b0] + r[4*k+0];
                    unsigned p1 = lbase[b1] + r[4*k+1];
                    unsigned p2 = lbase[b2] + r[4*k+2];
                    unsigned p3 = lbase[b3] + r[4*k+3];
                    staged[p0] = ((unsigned)(d0 & (BSIZE-1)) << 20) | (unsigned)vs[k].x;
                    staged[p1] = ((unsigned)(d1 & (BSIZE-1)) << 20) | (unsigned)vs[k].y;
                    staged[p2] = ((unsigned)(d2 & (BSIZE-1)) << 20) | (unsigned)vs[k].z;
                    staged[p3] = ((unsigned)(d3 & (BSIZE-1)) << 20) | (unsigned)vs[k].w;
                    sbuck[p0] = (unsigned char)b0;
                    sbuck[p1] = (unsigned char)b1;
                    sbuck[p2] = (unsigned char)b2;
                    sbuck[p3] = (unsigned char)b3;
                }
            }
            __syncthreads();
            unsigned tot = s_tot;
            for (unsigned pos = tid; pos < tot; pos += 256) {
                unsigned b = sbuck[pos];
                unsigned gp = sbase[b] + (pos - lbase[b]);
                if (gp < (unsigned)capG)
                    slab[((size_t)g * NBUK + b) * capG + gp] = staged[pos];
            }
            __syncthreads();
        }
        if (sid == 0 && tid < (E & 3)) {
            int i = (E & ~3) + tid;
            int d = dst[i];
            unsigned b = (unsigned)d >> BSHIFT;
            unsigned p = atomicAdd(&cursor[b], 1u);
            if (p < (unsigned)capG)
                slab[(size_t)b * capG + p] =
                    ((unsigned)(d & (BSIZE-1)) << 20) | (unsigned)src[i];
        }
    } else {
        // ---------------- h role: nodes [0, Nh) -----------------------------
        int hid = bid >> 1;
        int gwave = (hid * 256 + tid) >> 6;
        int lane = tid & 63;
        int half = lane >> 5;
        int l32  = lane & 31;
        int total_waves = (HGRID1 * 256) >> 6;
        float4 wv = ((const float4*)W)[l32];
        for (int node = gwave * 2 + half; node < Nh; node += total_waves * 2) {
            float4 xv = ((const float4*)(x + (size_t)node * 128))[l32];
            float v = xv.x * wv.x + xv.y * wv.y + xv.z * wv.z + xv.w * wv.w;
            #pragma unroll
            for (int d = 16; d >= 1; d >>= 1) v += __shfl_xor(v, d);
            if (l32 == 0) h[node] = v;
        }
    }
}

// ===== K2 (fused): hist role (blocks < 2*NBUK) ∥ h over [Nh, N) =============
__global__ void __launch_bounds__(FNT)
hist_h_kernel(const unsigned* __restrict__ slab, int capG,
              const unsigned* __restrict__ cursor,
              unsigned* __restrict__ deg0, unsigned* __restrict__ deg1,
              const float* __restrict__ x, const float* __restrict__ W,
              float* __restrict__ h, int Nh, int N, int NBUK, int nhblocks) {
    __shared__ unsigned hist[BSIZE];   // 16 KB
    int bp = blockIdx.x, tid = threadIdx.x;

    if (bp < 2 * NBUK) {
        int b = bp >> 1, half = bp & 1;
        for (int t = tid; t < BSIZE; t += FNT) hist[t] = 0;
        __syncthreads();
        int g0 = half * 16;
        for (int gg = g0; gg < g0 + 16; gg += 8) {
            unsigned n[8], maxn = 0;
            const unsigned* sp[8];
            #pragma unroll
            for (int k = 0; k < 8; ++k) {
                unsigned nn = cursor[(gg + k) * 256 + b];
                if (nn > (unsigned)capG) nn = capG;
                n[k] = nn; if (nn > maxn) maxn = nn;
                sp[k] = slab + ((size_t)(gg + k) * NBUK + b) * capG;
            }
            for (unsigned i = tid; i < maxn; i += FNT) {
                unsigned e[8];
                #pragma unroll
                for (int k = 0; k < 8; ++k) e[k] = (i < n[k]) ? sp[k][i] : 0xFFFFFFFFu;
                #pragma unroll
                for (int k = 0; k < 8; ++k)
                    if (e[k] != 0xFFFFFFFFu) atomicAdd(&hist[e[k] >> 20], 1u);
            }
        }
        __syncthreads();
        int base = b << BSHIFT;
        int lim = N - base; if (lim > BSIZE) lim = BSIZE;
        unsigned* degP = half ? deg1 : deg0;
        for (int t = tid; t < lim; t += FNT) degP[base + t] = hist[t];
    } else {
        int hb = bp - 2 * NBUK;
        int gwave = (hb * FNT + tid) >> 6;
        int lane = tid & 63;
        int half = lane >> 5;
        int l32  = lane & 31;
        int total_waves = (nhblocks * FNT) >> 6;
        float4 wv = ((const float4*)W)[l32];
        for (int node = Nh + gwave * 2 + half; node < N; node += total_waves * 2) {
            float4 xv = ((const float4*)(x + (size_t)node * 128))[l32];
            float v = xv.x * wv.x + xv.y * wv.y + xv.z * wv.z + xv.w * wv.w;
            #pragma unroll
            for (int d = 16; d >= 1; d >>= 1) v += __shfl_xor(v, d);
            if (l32 == 0) h[node] = v;
        }
    }
}

// ===== K3: finalize: dinv -> hsh, pkw (streaming, tiny) =====================
__global__ void finalize_kernel(const float* __restrict__ h,
                                const unsigned* __restrict__ deg0,
                                const unsigned* __restrict__ deg1,
                                const int* __restrict__ batch,
                                unsigned short* __restrict__ hsh,
                                unsigned* __restrict__ pkw, int N) {
    int i = blockIdx.x * blockDim.x + threadIdx.x;
    int stride = gridDim.x * blockDim.x;
    for (; i < N; i += stride) {
        float di = rsqrtf((float)(deg0[i] + deg1[i] + 1u));
        hsh[i] = __half_as_ushort(__float2half(di * h[i]));
        pkw[i] = ((unsigned)batch[i] << 16) | __half_as_ushort(__float2half(di));
    }
}

// ===== K4: aggregate — 4 quarter-blocks/bucket, 8-segment MLP, window pool ==
__global__ void __launch_bounds__(512)
aggregate_kernel(const unsigned* __restrict__ slab, int capG,
                 const unsigned* __restrict__ cursor,
                 const unsigned* __restrict__ pkw,
                 const unsigned short* __restrict__ hsh,
                 float* __restrict__ pooled, int N, int NBUK) {
    __shared__ unsigned pkw_s[BSIZE];        // 16 KB
    __shared__ float win[REPL * WPAD];       // 8.2 KB
    int bp = blockIdx.x, tid = threadIdx.x;
    int b = bp >> 2, q = bp & 3;
    int base = b << BSHIFT;
    int lim = N - base; if (lim > BSIZE) lim = BSIZE;

    for (int t = tid; t < BSIZE; t += 512) pkw_s[t] = (t < lim) ? pkw[base + t] : 0u;
    for (int t = tid; t < REPL * WPAD; t += 512) win[t] = 0.0f;
    __syncthreads();
    int g_lo = (int)(pkw_s[0] >> 16);
    int g_hi = (lim > 0) ? (int)(pkw_s[lim - 1] >> 16) : g_lo;
    int width = g_hi - g_lo + 1;
    bool windowed = (width <= WINDOW);
    int r = tid & (REPL - 1);

    int n0 = q * (BSIZE / 4);
    int n1 = (q + 1) * (BSIZE / 4); if (n1 > lim) n1 = lim;
    for (int t = n0 + tid; t < n1; t += 512) {
        unsigned w = pkw_s[t];
        float di = __half2float(__ushort_as_half((unsigned short)(w & 0xFFFFu)));
        float c = di * __half2float(__ushort_as_half(hsh[base + t]));
        if (windowed) atomicAdd(&win[r * WPAD + ((w >> 16) - g_lo)], c);
        else          atomicAdd(&pooled[w >> 16], c);
    }

    int g0 = q * 8;
    unsigned n[8], maxn = 0;
    const unsigned* sp[8];
    #pragma unroll
    for (int k = 0; k < 8; ++k) {
        unsigned nn = cursor[(g0 + k) * 256 + b];
        if (nn > (unsigned)capG) nn = capG;
        n[k] = nn; if (nn > maxn) maxn = nn;
        sp[k] = slab + ((size_t)(g0 + k) * NBUK + b) * capG;
    }
    for (unsigned i = tid; i < maxn; i += 512) {
        unsigned e[8]; bool v[8];
        #pragma unroll
        for (int k = 0; k < 8; ++k) { v[k] = (i < n[k]); e[k] = v[k] ? sp[k][i] : 0u; }
        unsigned w[8];
        #pragma unroll
        for (int k = 0; k < 8; ++k) w[k] = pkw_s[e[k] >> 20];
        unsigned short hb[8];
        #pragma unroll
        for (int k = 0; k < 8; ++k) hb[k] = hsh[e[k] & 0xFFFFFu];
        #pragma unroll
        for (int k = 0; k < 8; ++k) {
            float hv = __half2float(__ushort_as_half(hb[k]));
            float di = __half2float(__ushort_as_half((unsigned short)(w[k] & 0xFFFFu)));
            float c = v[k] ? hv * di : 0.0f;
            if (windowed) atomicAdd(&win[r * WPAD + ((w[k] >> 16) - g_lo)], c);
            else if (v[k]) atomicAdd(&pooled[w[k] >> 16], c);
        }
    }
    __syncthreads();
    if (windowed) {
        for (int g = tid; g < width; g += 512) {
            float s = 0.0f;
            #pragma unroll
            for (int rr = 0; rr < REPL; ++rr) s += win[rr * WPAD + g];
            atomicAdd(&pooled[g_lo + g], s);
        }
    }
}

// ===== K5: affine ==========================================================
__global__ void out_kernel(const float* __restrict__ pooled,
                           const float* __restrict__ pp_w,
                           const float* __restrict__ pp_b,
                           float* __restrict__ out) {
    int g = blockIdx.x * blockDim.x + threadIdx.x;
    if (g < NUM_GRAPHS) out[g] = pooled[g] * pp_w[0] + pp_b[0];
}

// ===== Fallback path (tiny ws / oversized N): correctness only =============
__global__ void deg_atomic_kernel(const int* __restrict__ dst, int E,
                                  unsigned* __restrict__ deg) {
    int tid = blockIdx.x * blockDim.x + threadIdx.x;
    int stride = gridDim.x * blockDim.x;
    for (int i = tid; i < E; i += stride) atomicAdd(&deg[dst[i]], 1u);
}

__global__ void node_fb_kernel(const float* __restrict__ x,
                               const float* __restrict__ W,
                               const unsigned* __restrict__ deg,
                               const int* __restrict__ batch,
                               unsigned short* __restrict__ hsh,
                               unsigned* __restrict__ pkw, int N) {
    int gtid = blockIdx.x * blockDim.x + threadIdx.x;
    int wave = gtid >> 6;
    int lane = threadIdx.x & 63;
    int half = lane >> 5;
    int l32  = lane & 31;
    int node = wave * 2 + half;
    if (node >= N) return;
    float4 xv = ((const float4*)(x + (size_t)node * 128))[l32];
    float4 wv = ((const float4*)W)[l32];
    float v = xv.x * wv.x + xv.y * wv.y + xv.z * wv.z + xv.w * wv.w;
    #pragma unroll
    for (int d = 16; d >= 1; d >>= 1) v += __shfl_xor(v, d);
    if (l32 == 0) {
        float di = rsqrtf((float)(deg[node] + 1u));
        hsh[node] = __half_as_ushort(__float2half(di * v));
        pkw[node] = ((unsigned)batch[node] << 16) | __half_as_ushort(__float2half(di));
    }
}

__global__ void pool_self_fb_kernel(const unsigned short* __restrict__ hsh,
                                    const unsigned* __restrict__ pkw,
                                    float* __restrict__ pooled, int N) {
    int i = blockIdx.x * blockDim.x + threadIdx.x;
    if (i >= N) return;
    unsigned w = pkw[i];
    float di = __half2float(__ushort_as_half((unsigned short)(w & 0xFFFFu)));
    atomicAdd(&pooled[w >> 16], di * __half2float(__ushort_as_half(hsh[i])));
}

__global__ void __launch_bounds__(512)
edge_direct_kernel(const int* __restrict__ src, const int* __restrict__ dst, int E,
                   const unsigned short* __restrict__ hsh,
                   const unsigned* __restrict__ pkw,
                   float* __restrict__ pooled) {
    __shared__ float pool[NUM_GRAPHS];
    for (int g = threadIdx.x; g < NUM_GRAPHS; g += 512) pool[g] = 0.0f;
    __syncthreads();
    int tid = blockIdx.x * 512 + threadIdx.x;
    int stride = gridDim.x * 512;
    for (int i = tid; i < E; i += stride) {
        unsigned w = pkw[dst[i]];
        float c = __half2float(__ushort_as_half(hsh[src[i]])) *
                  __half2float(__ushort_as_half((unsigned short)(w & 0xFFFFu)));
        atomicAdd(&pool[w >> 16], c);
    }
    __syncthreads();
    for (int g = threadIdx.x; g < NUM_GRAPHS; g += 512)
        if (pool[g] != 0.0f) atomicAdd(&pooled[g], pool[g]);
}

extern "C" void kernel_launch(void* const* d_in, const int* in_sizes, int n_in,
                              void* d_out, int out_size, void* d_ws, size_t ws_size,
                              hipStream_t stream) {
    const float* x    = (const float*)d_in[0];
    const float* W    = (const float*)d_in[1];
    const float* pp_w = (const float*)d_in[2];
    const float* pp_b = (const float*)d_in[3];
    const int*   ei   = (const int*)d_in[4];
    const int*   batch= (const int*)d_in[5];
    float* out = (float*)d_out;

    const int E = in_sizes[4] / 2;
    const int N = in_sizes[5];
    const int* src = ei;
    const int* dst = ei + E;
    int NBUK = (N + BSIZE - 1) >> BSHIFT;
    int nchunks = (E + CHUNK - 1) / CHUNK;

    char* ws = (char*)d_ws;
    size_t off = 0;
    auto alloc = [&](size_t bytes) {
        size_t o = off; off = (off + bytes + 255) & ~(size_t)255; return o;
    };
    size_t zero_bytes = (size_t)NUM_GRAPHS * 4 + (size_t)NGRP * 256 * 4;
    size_t zero_off   = alloc(zero_bytes);
    float*    pooled = (float*)(ws + zero_off);
    unsigned* cursor = (unsigned*)(ws + zero_off + (size_t)NUM_GRAPHS * 4);

    size_t h_off    = alloc((size_t)N * 4);
    size_t deg0_off = alloc((size_t)N * 4);      // also fallback deg
    size_t deg1_off = alloc((size_t)N * 4);
    size_t hsh_off  = alloc((size_t)N * 2);
    size_t pkw_off  = alloc((size_t)N * 4);

    int meanG = E / (NBUK * NGRP) + 1;
    int capG = (meanG + meanG / 8 + 512 + 3) & ~3;   // ~17 sigma, 16B-aligned
    size_t slab_off = alloc((size_t)NGRP * NBUK * (size_t)capG * 4);

    bool fast_ok = (NBUK <= 256) && (N <= (1 << 20)) && (off <= ws_size);

    float*          h    = (float*)(ws + h_off);
    unsigned*       deg0 = (unsigned*)(ws + deg0_off);
    unsigned*       deg1 = (unsigned*)(ws + deg1_off);
    unsigned short* hsh  = (unsigned short*)(ws + hsh_off);
    unsigned*       pkw  = (unsigned*)(ws + pkw_off);
    unsigned*       slab = (unsigned*)(ws + slab_off);

    hipMemsetAsync(ws + zero_off, 0, zero_bytes, stream);

    if (fast_ok) {
        int Nh = N >> 1;
        scatter_h_kernel<<<SGRID + HGRID1, 256, 0, stream>>>(
            src, dst, E, nchunks, NBUK, capG, cursor, slab, x, W, h, Nh);
        int nhblocks = 2048;   // h-role blocks in dispatch 2
        hist_h_kernel<<<2 * NBUK + nhblocks, FNT, 0, stream>>>(
            slab, capG, cursor, deg0, deg1, x, W, h, Nh, N, NBUK, nhblocks);
        finalize_kernel<<<1024, 256, 0, stream>>>(h, deg0, deg1, batch, hsh, pkw, N);
        aggregate_kernel<<<4 * NBUK, 512, 0, stream>>>(slab, capG, cursor, pkw,
                                                       hsh, pooled, N, NBUK);
    } else {
        hipMemsetAsync(deg0, 0, (size_t)N * 4, stream);
        deg_atomic_kernel<<<2048, 256, 0, stream>>>(dst, E, deg0);
        int node_blocks = (N + 7) / 8;
        node_fb_kernel<<<node_blocks, 256, 0, stream>>>(x, W, deg0, batch, hsh, pkw, N);
        pool_self_fb_kernel<<<(N + 255) / 256, 256, 0, stream>>>(hsh, pkw, pooled, N);
        edge_direct_kernel<<<512, 512, 0, stream>>>(src, dst, E, hsh, pkw, pooled);
    }

    out_kernel<<<(NUM_GRAPHS + 255) / 256, 256, 0, stream>>>(pooled, pp_w, pp_b, out);
}